// Round 11
// baseline (228.515 us; speedup 1.0000x reference)
//
#include <hip/hip_runtime.h>
#include <hip/hip_cooperative_groups.h>
#include <math.h>

// Problem constants (from reference)
#define NN      131072u         // ROWS*COLS*P = 64*64*32
#define Q       10
#define T1      8
#define GRID    1024            // 4 blocks/CU -> safely co-resident for cooperative launch
#define BLOCK   256
#define CHUNK   (E_F2 / GRID)   // 10240 float2s per block = 40 iters * 256 threads exactly

// d_out layout (float32, concatenated in return order):
//   [0, 10)                         prediction
//   [10, 10 + N*Q*T1)               voter_in[0]   (10,485,760)
//   [10 + N*Q*T1, ... + 2*N*Q*T1)   votes         (20,971,520)
#define VIN0_OFF   10u
#define VIN0_SZ    (NN * Q * T1)            // 10485760
#define VOTES_OFF  (VIN0_OFF + VIN0_SZ)     // 10485770 (8B-aligned)
#define VOTES_SZ   (2u * NN * Q * T1)       // 20971520
#define E_F2       (VOTES_SZ / 2u)          // 10,485,760 float2s of votes

namespace cg = cooperative_groups;

// Single fused kernel: R8's proven contiguous-chunk body + ballot tally,
// then grid-wide sync and block-0 reduction/argmax (replaces the pred dispatch).
// Cross-XCD tally visibility via agent-scope release/acquire atomics.
__global__ __launch_bounds__(BLOCK) void dtnn_fused(
    const float* __restrict__ spikes,   // (N,)
    const float* __restrict__ weights,  // (2, N, Q, T1)
    float* __restrict__ out,
    unsigned int* __restrict__ tallies) // (Q, GRID)
{
    const unsigned int lane = threadIdx.x & 63u;
    const unsigned int wid  = threadIdx.x >> 6;   // 4 waves/block

    float2* __restrict__ votes2 = (float2*)(out + VOTES_OFF);
    float2* __restrict__ vin2   = (float2*)(out + VIN0_OFF);

    unsigned int acc = 0u;   // lane k (<10) accumulates tally for class k

    const unsigned int jbase = blockIdx.x * (unsigned int)CHUNK + threadIdx.x;
    #pragma unroll 1
    for (unsigned int it = 0; it < CHUNK / BLOCK; ++it) {
        const unsigned int j    = jbase + it * BLOCK;
        const unsigned int r    = j >> 2;          // (s,i,q) row
        const unsigned int slot = j & 3u;          // which float2 of the 8-bin row
        const unsigned int ri   = r / Q;           // s*N + i
        const unsigned int q    = r - Q * ri;      // r % 10
        const unsigned int i    = ri & (NN - 1u);

        float v = spikes[i];
        if (v >= 7.0f && !isinf(v)) v = 7.0f;      // clamp finite >= tau_eff
        const int  tv    = (int)v;
        const bool valid = (v >= 0.0f) && (v < 8.0f) && ((float)tv == v);
        const bool owns  = valid && ((unsigned)(tv >> 1) == slot);

        float2 o   = make_float2(0.0f, 0.0f);
        bool   inc = false;
        if (owns) {                                 // exec-masked scalar load (R3/R8-proven)
            const float w    = weights[r * 8u + (unsigned)tv];
            const float vote = (w >= 3.5f) ? 1.0f : 0.0f;
            if (tv & 1) o.y = vote; else o.x = vote;
            inc = (vote != 0.0f);
        }
        votes2[j] = o;

        if (r < NN * Q) {                           // s == 0: emit voter_in[0]
            float2 h = make_float2(0.0f, 0.0f);
            if (owns) { if (tv & 1) h.y = 1.0f; else h.x = 1.0f; }
            vin2[j] = h;
        }

        // Wave-level tally: 10 ballots, zero LDS traffic.
        #pragma unroll
        for (int k = 0; k < Q; ++k) {
            const unsigned long long m = __ballot(inc && (q == (unsigned)k));
            if (lane == (unsigned)k) acc += (unsigned)__popcll(m);
        }
    }

    // Combine 4 waves' lane-resident tallies; publish with agent-scope release.
    __shared__ unsigned int lt[4 * Q];
    if (lane < Q) lt[wid * Q + lane] = acc;
    __syncthreads();
    if (threadIdx.x < Q) {
        const unsigned int partial =
            lt[threadIdx.x] + lt[Q + threadIdx.x] + lt[2 * Q + threadIdx.x] + lt[3 * Q + threadIdx.x];
        __hip_atomic_store(&tallies[threadIdx.x * GRID + blockIdx.x], partial,
                           __ATOMIC_RELEASE, __HIP_MEMORY_SCOPE_AGENT);
    }

    cg::this_grid().sync();

    // ---- block 0: reduce (Q, GRID) partials and write prediction ----
    if (blockIdx.x == 0) {
        __shared__ unsigned int red[4];
        __shared__ unsigned int sums[Q];
        const unsigned int tid = threadIdx.x;
        for (int q = 0; q < Q; ++q) {
            unsigned int s = 0;
            #pragma unroll
            for (int it = 0; it < GRID / BLOCK; ++it)   // 4 coalesced loads/thread
                s += __hip_atomic_load(&tallies[q * GRID + it * BLOCK + tid],
                                       __ATOMIC_ACQUIRE, __HIP_MEMORY_SCOPE_AGENT);
            #pragma unroll
            for (int off = 32; off >= 1; off >>= 1)
                s += __shfl_down(s, off, 64);
            if (lane == 0) red[wid] = s;
            __syncthreads();
            if (tid == 0) sums[q] = red[0] + red[1] + red[2] + red[3];
            __syncthreads();
        }
        if (tid == 0) {
            unsigned int best = sums[0]; int bi = 0;
            #pragma unroll
            for (int k = 1; k < Q; ++k)
                if (sums[k] > best) { best = sums[k]; bi = k; }   // first-index tie-break
            #pragma unroll
            for (int k = 0; k < Q; ++k) out[k] = (k == bi) ? 1.0f : 0.0f;
        }
    }
}

extern "C" void kernel_launch(void* const* d_in, const int* in_sizes, int n_in,
                              void* d_out, int out_size, void* d_ws, size_t ws_size,
                              hipStream_t stream) {
    const float* spikes  = (const float*)d_in[0];   // (64,64,32) float32
    const float* weights = (const float*)d_in[1];   // (2, N, Q, T1) float32
    float* out = (float*)d_out;
    unsigned int* tallies = (unsigned int*)d_ws;    // Q * GRID uints = 40 KB

    void* args[] = { (void*)&spikes, (void*)&weights, (void*)&out, (void*)&tallies };
    hipLaunchCooperativeKernel((const void*)dtnn_fused, dim3(GRID), dim3(BLOCK),
                               args, 0, stream);
}

// Round 12
// 40.833 us; speedup vs baseline: 5.5964x; 5.5964x over previous
//
#include <hip/hip_runtime.h>
#include <math.h>

// Problem constants (from reference)
#define NN      131072          // ROWS*COLS*P = 64*64*32
#define Q       10
#define T1      8
#define GRID    2048
#define BLOCK   256
#define CHUNK   (E_F2 / GRID)   // 5120 float2s per block = 20 iters * 256 threads exactly

// d_out layout (float32, concatenated in return order):
//   [0, 10)                         prediction
//   [10, 10 + N*Q*T1)               voter_in[0]   (10,485,760)
//   [10 + N*Q*T1, ... + 2*N*Q*T1)   votes         (20,971,520)
#define VIN0_OFF   10u
#define VIN0_SZ    (NN * Q * T1)            // 10485760
#define VOTES_OFF  (VIN0_OFF + VIN0_SZ)     // 10485770 (8B-aligned)
#define VOTES_SZ   (2u * NN * Q * T1)       // 20971520
#define E_F2       (VOTES_SZ / 2u)          // 10,485,760 float2s of votes

// Best-known configuration (R8, 40.9 us):
//  - one thread per float2 of votes; contiguous per-block chunks (sequential
//    HBM streams per block -> row-buffer locality; grid-stride sweeps were
//    ~1.4 us slower; all latency/VALU/store-width levers measured null)
//  - exec-masked scalar weight load (1 of 8 bins needed; lines fully touched)
//  - wave-ballot tally: zero LDS traffic in-loop (LDS atomics cost ~25 us, R2)
//  - per-block partial stores + tiny second dispatch for reduce/argmax
//    (cooperative-launch fusion forced device-coherent stores: 5.6x slower)
__global__ __launch_bounds__(BLOCK) void dtnn_main(
    const float* __restrict__ spikes,   // (N,)
    const float* __restrict__ weights,  // (2, N, Q, T1)
    float* __restrict__ out,
    unsigned int* __restrict__ tallies) // (Q, GRID)
{
    const unsigned int lane = threadIdx.x & 63u;
    const unsigned int wid  = threadIdx.x >> 6;   // 4 waves/block

    float2* __restrict__ votes2 = (float2*)(out + VOTES_OFF);
    float2* __restrict__ vin2   = (float2*)(out + VIN0_OFF);

    unsigned int acc = 0u;   // lane k (<10) accumulates tally for class k

    const unsigned int jbase = blockIdx.x * (unsigned int)CHUNK + threadIdx.x;
    #pragma unroll 1
    for (unsigned int it = 0; it < CHUNK / BLOCK; ++it) {
        const unsigned int j    = jbase + it * BLOCK;
        const unsigned int r    = j >> 2;          // (s,i,q) row
        const unsigned int slot = j & 3u;          // which float2 of the 8-bin row
        const unsigned int ri   = r / Q;           // s*N + i
        const unsigned int q    = r - Q * ri;      // r % 10
        const unsigned int i    = ri & (NN - 1u);

        float v = spikes[i];
        if (v >= 7.0f && !isinf(v)) v = 7.0f;      // clamp finite >= tau_eff
        const int  tv    = (int)v;
        const bool valid = (v >= 0.0f) && (v < 8.0f) && ((float)tv == v);
        const bool owns  = valid && ((unsigned)(tv >> 1) == slot);

        float2 o   = make_float2(0.0f, 0.0f);
        bool   inc = false;
        if (owns) {                                 // exec-masked scalar load
            const float w    = weights[r * 8u + (unsigned)tv];
            const float vote = (w >= 3.5f) ? 1.0f : 0.0f;
            if (tv & 1) o.y = vote; else o.x = vote;
            inc = (vote != 0.0f);
        }
        votes2[j] = o;

        if (r < NN * Q) {                           // s == 0 (block-uniform branch)
            float2 h = make_float2(0.0f, 0.0f);
            if (owns) { if (tv & 1) h.y = 1.0f; else h.x = 1.0f; }
            vin2[j] = h;
        }

        // Wave-level tally: 10 ballots, zero LDS traffic.
        #pragma unroll
        for (int k = 0; k < Q; ++k) {
            const unsigned long long m = __ballot(inc && (q == (unsigned)k));
            if (lane == (unsigned)k) acc += (unsigned)__popcll(m);
        }
    }

    // Combine 4 waves' lane-resident tallies via plain LDS stores.
    __shared__ unsigned int lt[4 * Q];
    if (lane < Q) lt[wid * Q + lane] = acc;
    __syncthreads();
    if (threadIdx.x < Q) {
        tallies[threadIdx.x * GRID + blockIdx.x] =
            lt[threadIdx.x] + lt[Q + threadIdx.x] + lt[2 * Q + threadIdx.x] + lt[3 * Q + threadIdx.x];
    }
}

// One wave per class: coalesced partial loads + shuffle reduction.
__global__ __launch_bounds__(64 * Q) void dtnn_pred(
    const unsigned int* __restrict__ tallies,  // (Q, GRID)
    float* __restrict__ out)
{
    const unsigned int lane = threadIdx.x & 63u;
    const unsigned int q    = threadIdx.x >> 6;    // 0..9

    unsigned int s = 0;
    #pragma unroll
    for (int it = 0; it < GRID / 64; ++it)
        s += tallies[q * GRID + it * 64 + lane];
    #pragma unroll
    for (int off = 32; off >= 1; off >>= 1)
        s += __shfl_down(s, off, 64);

    __shared__ unsigned int sums[Q];
    if (lane == 0) sums[q] = s;
    __syncthreads();

    if (threadIdx.x == 0) {
        unsigned int best = sums[0]; int bi = 0;
        #pragma unroll
        for (int k = 1; k < Q; ++k)
            if (sums[k] > best) { best = sums[k]; bi = k; }   // first-index tie-break
        #pragma unroll
        for (int k = 0; k < Q; ++k) out[k] = (k == bi) ? 1.0f : 0.0f;
    }
}

extern "C" void kernel_launch(void* const* d_in, const int* in_sizes, int n_in,
                              void* d_out, int out_size, void* d_ws, size_t ws_size,
                              hipStream_t stream) {
    const float* spikes  = (const float*)d_in[0];   // (64,64,32) float32
    const float* weights = (const float*)d_in[1];   // (2, N, Q, T1) float32
    float* out = (float*)d_out;
    unsigned int* tallies = (unsigned int*)d_ws;    // Q * GRID uints = 80 KB

    dtnn_main<<<GRID, BLOCK, 0, stream>>>(spikes, weights, out, tallies);
    dtnn_pred<<<1, 64 * Q, 0, stream>>>(tallies, out);
}